// Round 1
// baseline (128.638 us; speedup 1.0000x reference)
//
#include <hip/hip_runtime.h>
#include <hip/hip_bf16.h>

#define BATCH 4096
#define NH    1024
#define KCAT  2048   // x(1024) | h(1024)
#define NJ    4096   // 4 gates * 1024

typedef __bf16 bf16x8 __attribute__((ext_vector_type(8)));
typedef float  f32x4  __attribute__((ext_vector_type(4)));
typedef unsigned short u16x8 __attribute__((ext_vector_type(8)));

struct WPtrs { const float* wx[4]; const float* wh[4]; };
struct BPtrs { const float* bx[4]; const float* bh[4]; };

__device__ __forceinline__ unsigned short f2b(float f) {
  union { float f; unsigned u; } v; v.f = f;
  return (unsigned short)((v.u + 0x7fffu + ((v.u >> 16) & 1u)) >> 16);  // RNE
}

__device__ __forceinline__ void gload_lds16(const void* g, void* l) {
  __builtin_amdgcn_global_load_lds(
      (const __attribute__((address_space(1))) unsigned int*)g,
      (__attribute__((address_space(3))) unsigned int*)l, 16, 0, 0);
}

__device__ __forceinline__ float sigmoid_f(float x) {
  x = fminf(fmaxf(x, -30.f), 30.f);
  return 1.f / (1.f + __expf(-x));
}
__device__ __forceinline__ float tanh_f(float x) {
  x = fminf(fmaxf(x, -15.f), 15.f);
  float e = __expf(2.f * x);
  return (e - 1.f) / (e + 1.f);
}

// ---------------- pack kernels ----------------

// A_cat[row][k] = k<1024 ? x[row][k] : h[row][k-1024], bf16, row-major K=2048
__global__ __launch_bounds__(256) void pack_a(const float* __restrict__ x,
                                              const float* __restrict__ h,
                                              __hip_bfloat16* __restrict__ Acat) {
  int t = blockIdx.x * 256 + threadIdx.x;
  int base = t * 8;
  int row = base >> 11;
  int k   = base & 2047;
  const float* src = (k < 1024) ? (x + (size_t)row * 1024 + k)
                                : (h + (size_t)row * 1024 + (k - 1024));
  float4 v0 = ((const float4*)src)[0];
  float4 v1 = ((const float4*)src)[1];
  u16x8 o;
  o[0]=f2b(v0.x); o[1]=f2b(v0.y); o[2]=f2b(v0.z); o[3]=f2b(v0.w);
  o[4]=f2b(v1.x); o[5]=f2b(v1.y); o[6]=f2b(v1.z); o[7]=f2b(v1.w);
  *(u16x8*)((unsigned short*)Acat + base) = o;
}

// B_cat[j][k]: j = (n>>4)*64 + g*16 + (n&15); k<1024 -> W_xg[n][k] else W_hg[n][k-1024]
__global__ __launch_bounds__(256) void pack_b(WPtrs W, __hip_bfloat16* __restrict__ Bcat) {
  int t = blockIdx.x * 256 + threadIdx.x;
  int base = t * 8;
  int j = base >> 11;          // one j per block (2048 = 256*8)
  int k = base & 2047;
  int n = ((j >> 6) << 4) + (j & 15);
  int g = (j >> 4) & 3;
  const float* src = (k < 1024) ? (W.wx[g] + (size_t)n * 1024 + k)
                                : (W.wh[g] + (size_t)n * 1024 + (k - 1024));
  float4 v0 = ((const float4*)src)[0];
  float4 v1 = ((const float4*)src)[1];
  u16x8 o;
  o[0]=f2b(v0.x); o[1]=f2b(v0.y); o[2]=f2b(v0.z); o[3]=f2b(v0.w);
  o[4]=f2b(v1.x); o[5]=f2b(v1.y); o[6]=f2b(v1.z); o[7]=f2b(v1.w);
  *(u16x8*)((unsigned short*)Bcat + base) = o;
}

// biasc[g*1024 + n] = b_xg[n] + b_hg[n]
__global__ __launch_bounds__(256) void pack_bias(BPtrs B, float* __restrict__ biasc) {
  int i = blockIdx.x * 256 + threadIdx.x;   // 0..4095
  int g = i >> 10, n = i & 1023;
  biasc[i] = B.bx[g][n] + B.bh[g][n];
}

// ---------------- fused GEMM + gate epilogue ----------------
// C[row][j] = sum_k Acat[row][k]*Bcat[j][k]; 128x128 tile, BK=64, 4 waves (2x2).
// Within a wave's 64 cols, the 4 col-fragments are gates f,i,o,c for the same 16 n.
__global__ __launch_bounds__(256) void lstm_gemm(
    const __hip_bfloat16* __restrict__ Acat,
    const __hip_bfloat16* __restrict__ Bcat,
    const float* __restrict__ biasc,
    const float* __restrict__ cell,
    float* __restrict__ outH, float* __restrict__ outC) {
  __shared__ unsigned short Asm[128 * 64];
  __shared__ unsigned short Bsm[128 * 64];

  const int tid  = threadIdx.x;
  const int w    = tid >> 6;
  const int lane = tid & 63;
  const int wr   = w >> 1;     // wave row 0..1
  const int wc   = w & 1;      // wave col 0..1
  const int bx   = blockIdx.x; // N tiles (32)
  const int by   = blockIdx.y; // M tiles (32)

  const int lr = lane & 15;
  const int lk = (lane >> 4) * 8;

  f32x4 acc[4][4] = {};

  const unsigned short* Ag = (const unsigned short*)Acat + (size_t)(by * 128) * KCAT;
  const unsigned short* Bg = (const unsigned short*)Bcat + (size_t)(bx * 128) * KCAT;

  for (int kt = 0; kt < KCAT; kt += 64) {
    // stage A and B tiles: 128 rows x 64 k, linear LDS, 16B per lane
#pragma unroll
    for (int i = 0; i < 4; ++i) {
      int r0 = i * 32 + w * 8;  // wave-uniform
      gload_lds16(Ag + (size_t)(r0 + (lane >> 3)) * KCAT + kt + (lane & 7) * 8,
                  &Asm[r0 * 64]);
    }
#pragma unroll
    for (int i = 0; i < 4; ++i) {
      int r0 = i * 32 + w * 8;
      gload_lds16(Bg + (size_t)(r0 + (lane >> 3)) * KCAT + kt + (lane & 7) * 8,
                  &Bsm[r0 * 64]);
    }
    __syncthreads();

#pragma unroll
    for (int kk = 0; kk < 64; kk += 32) {
      bf16x8 a[4], b[4];
#pragma unroll
      for (int m = 0; m < 4; ++m)
        a[m] = *(const bf16x8*)(const void*)&Asm[(wr * 64 + m * 16 + lr) * 64 + kk + lk];
#pragma unroll
      for (int c = 0; c < 4; ++c)
        b[c] = *(const bf16x8*)(const void*)&Bsm[(wc * 64 + c * 16 + lr) * 64 + kk + lk];
#pragma unroll
      for (int m = 0; m < 4; ++m)
#pragma unroll
        for (int c = 0; c < 4; ++c)
          acc[m][c] = __builtin_amdgcn_mfma_f32_16x16x32_bf16(a[m], b[c], acc[m][c], 0, 0, 0);
    }
    __syncthreads();
  }

  // epilogue: col-frag c == gate (f,i,o,c); n identical across c -> in-lane fusion
  const int n = bx * 32 + wc * 16 + lr;
  const float bfv = biasc[n];
  const float biv = biasc[1024 + n];
  const float bov = biasc[2048 + n];
  const float bcv = biasc[3072 + n];

#pragma unroll
  for (int m = 0; m < 4; ++m) {
    int row0 = by * 128 + wr * 64 + m * 16 + (lane >> 4) * 4;
#pragma unroll
    for (int q = 0; q < 4; ++q) {
      int row = row0 + q;
      float pf = acc[m][0][q] + bfv;
      float pi = acc[m][1][q] + biv;
      float po = acc[m][2][q] + bov;
      float pc = acc[m][3][q] + bcv;
      float fg = sigmoid_f(pf);
      float ig = sigmoid_f(pi);
      float og = sigmoid_f(po);
      float cg = tanh_f(pc);
      float cold = cell[(size_t)row * NH + n];
      float cn = fg * cold + ig * cg;
      float hn = og * tanh_f(cn);
      outH[(size_t)row * NH + n] = hn;
      outC[(size_t)row * NH + n] = cn;
    }
  }
}

extern "C" void kernel_launch(void* const* d_in, const int* in_sizes, int n_in,
                              void* d_out, int out_size, void* d_ws, size_t ws_size,
                              hipStream_t stream) {
  const float* x    = (const float*)d_in[0];
  const float* h    = (const float*)d_in[1];
  const float* cell = (const float*)d_in[2];
  WPtrs wp; BPtrs bp;
  for (int g = 0; g < 4; ++g) {
    wp.wx[g] = (const float*)d_in[3 + 2 * g];    // W_xf, W_xi, W_xo, W_xc
    bp.bx[g] = (const float*)d_in[4 + 2 * g];
    wp.wh[g] = (const float*)d_in[11 + 2 * g];   // W_hf, W_hi, W_ho, W_hc
    bp.bh[g] = (const float*)d_in[12 + 2 * g];
  }

  char* ws = (char*)d_ws;
  __hip_bfloat16* Acat = (__hip_bfloat16*)ws;                                   // 16 MB
  __hip_bfloat16* Bcat = (__hip_bfloat16*)(ws + (size_t)BATCH * KCAT * 2);      // 16 MB
  float* biasc = (float*)(ws + (size_t)BATCH * KCAT * 2 + (size_t)NJ * KCAT * 2); // 16 KB

  float* outH = (float*)d_out;
  float* outC = outH + (size_t)BATCH * NH;

  pack_a<<<BATCH * KCAT / 8 / 256, 256, 0, stream>>>(x, h, Acat);
  pack_b<<<NJ * KCAT / 8 / 256, 256, 0, stream>>>(wp, Bcat);
  pack_bias<<<NJ / 1024 * 4, 256, 0, stream>>>(bp, biasc);

  dim3 grid(32, 32);
  lstm_gemm<<<grid, 256, 0, stream>>>(Acat, Bcat, biasc, cell, outH, outC);
}

// Round 2
// 91.134 us; speedup vs baseline: 1.4115x; 1.4115x over previous
//
#include <hip/hip_runtime.h>
#include <hip/hip_bf16.h>

#define BATCH 4096
#define NH    1024
#define KCAT  2048   // x(1024) | h(1024)
#define NJ    4096   // 4 gates * 1024
#define NT    (KCAT / 64)   // 32 K-tiles

typedef __bf16 bf16x8 __attribute__((ext_vector_type(8)));
typedef float  f32x4  __attribute__((ext_vector_type(4)));
typedef unsigned short u16x8 __attribute__((ext_vector_type(8)));

struct WPtrs { const float* wx[4]; const float* wh[4]; };
struct BPtrs { const float* bx[4]; const float* bh[4]; };

__device__ __forceinline__ unsigned short f2b(float f) {
  union { float f; unsigned u; } v; v.f = f;
  return (unsigned short)((v.u + 0x7fffu + ((v.u >> 16) & 1u)) >> 16);  // RNE
}

__device__ __forceinline__ void gload_lds16(const void* g, void* l) {
  __builtin_amdgcn_global_load_lds(
      (const __attribute__((address_space(1))) unsigned int*)g,
      (__attribute__((address_space(3))) unsigned int*)l, 16, 0, 0);
}

__device__ __forceinline__ float sigmoid_f(float x) {
  x = fminf(fmaxf(x, -30.f), 30.f);
  return 1.f / (1.f + __expf(-x));
}
__device__ __forceinline__ float tanh_f(float x) {
  x = fminf(fmaxf(x, -15.f), 15.f);
  float e = __expf(2.f * x);
  return (e - 1.f) / (e + 1.f);
}

// ---------------- pack kernels ----------------

__global__ __launch_bounds__(256) void pack_a(const float* __restrict__ x,
                                              const float* __restrict__ h,
                                              __hip_bfloat16* __restrict__ Acat) {
  int t = blockIdx.x * 256 + threadIdx.x;
  int base = t * 8;
  int row = base >> 11;
  int k   = base & 2047;
  const float* src = (k < 1024) ? (x + (size_t)row * 1024 + k)
                                : (h + (size_t)row * 1024 + (k - 1024));
  float4 v0 = ((const float4*)src)[0];
  float4 v1 = ((const float4*)src)[1];
  u16x8 o;
  o[0]=f2b(v0.x); o[1]=f2b(v0.y); o[2]=f2b(v0.z); o[3]=f2b(v0.w);
  o[4]=f2b(v1.x); o[5]=f2b(v1.y); o[6]=f2b(v1.z); o[7]=f2b(v1.w);
  *(u16x8*)((unsigned short*)Acat + base) = o;
}

// B_cat[j][k]: j = (n>>4)*64 + g*16 + (n&15)
__global__ __launch_bounds__(256) void pack_b(WPtrs W, __hip_bfloat16* __restrict__ Bcat) {
  int t = blockIdx.x * 256 + threadIdx.x;
  int base = t * 8;
  int j = base >> 11;
  int k = base & 2047;
  int n = ((j >> 6) << 4) + (j & 15);
  int g = (j >> 4) & 3;
  const float* src = (k < 1024) ? (W.wx[g] + (size_t)n * 1024 + k)
                                : (W.wh[g] + (size_t)n * 1024 + (k - 1024));
  float4 v0 = ((const float4*)src)[0];
  float4 v1 = ((const float4*)src)[1];
  u16x8 o;
  o[0]=f2b(v0.x); o[1]=f2b(v0.y); o[2]=f2b(v0.z); o[3]=f2b(v0.w);
  o[4]=f2b(v1.x); o[5]=f2b(v1.y); o[6]=f2b(v1.z); o[7]=f2b(v1.w);
  *(u16x8*)((unsigned short*)Bcat + base) = o;
}

__global__ __launch_bounds__(256) void pack_bias(BPtrs B, float* __restrict__ biasc) {
  int i = blockIdx.x * 256 + threadIdx.x;
  int g = i >> 10, n = i & 1023;
  biasc[i] = B.bx[g][n] + B.bh[g][n];
}

// ---------------- 256x256 8-phase fused GEMM + LSTM epilogue ----------------
// BM=BN=256, BK=64, 8 waves (2M x 4N), per-wave 128x64 output (acc[8][4]).
// LDS 128 KiB: 2 buffers x (A 256x64 | B 256x64) bf16.
// Swizzle: read byte col ^= (row&7)<<4; stage pre-swizzles the GLOBAL source
// chunk (global_load_lds writes linearly). Stagger: tile t's phases stage
// [t+1 A-half0, t+1 A-half1, t+2 B-half0, t+2 B-half1] -> every stage targets
// a dead region; boundary s_waitcnt vmcnt(4) retires exactly tile t+1's data.
#define STAGE_HALF(Mg, MOFF, T, H, B)                                           \
  {                                                                             \
    _Pragma("unroll")                                                           \
    for (int i_ = 0; i_ < 2; ++i_) {                                            \
      const unsigned short* src_ =                                              \
          (Mg) + (size_t)((H) * 128 + i_ * 64 + strow) * KCAT + (T) * 64 +      \
          stchnk * 8;                                                           \
      unsigned short* dst_ =                                                    \
          &smem[(B) * 32768 + (MOFF) + (H) * 8192 + i_ * 4096 + w * 512];       \
      gload_lds16(src_, dst_);                                                  \
    }                                                                           \
  }

__global__ __launch_bounds__(512, 2) void lstm_gemm8(
    const unsigned short* __restrict__ Acat,
    const unsigned short* __restrict__ Bcat,
    const float* __restrict__ biasc,
    const float* __restrict__ cell,
    float* __restrict__ outH, float* __restrict__ outC) {
  __shared__ unsigned short smem[65536];  // 128 KiB

  const int tid  = threadIdx.x;
  const int w    = tid >> 6;    // 0..7
  const int lane = tid & 63;
  const int wr   = w >> 2;      // 0..1 (M)
  const int wc   = w & 3;       // 0..3 (N)
  const int lr   = lane & 15;
  const int cb0  = ((lane >> 4) & 3) * 16;   // 16B chunk within row
  const int sx   = (lr & 7) << 4;            // read-side swizzle XOR

  // XCD-aware bijective swizzle (256 blocks, 8 XCDs)
  const int bid = blockIdx.x;
  const int s   = (bid & 7) * 32 + (bid >> 3);
  const int bx  = s & 15;
  const int by  = s >> 4;

  const unsigned short* Ag = Acat + (size_t)(by * 256) * KCAT;
  const unsigned short* Bg = Bcat + (size_t)(bx * 256) * KCAT;

  // staging source mapping (pre-swizzled global chunk)
  const int strow  = w * 8 + (lane >> 3);              // row within 64-row block
  const int stchnk = (lane & 7) ^ ((lane >> 3) & 7);   // swizzled src chunk

  // per-thread read base byte offsets into smem
  const int arow0 = (wr * 128 + lr) * 128;          // + m*2048 + colb
  const int brow0 = 32768 + (wc * 64 + lr) * 128;   // + n*2048 + colb
  const int colb0 = cb0 ^ sx;
  const int colb1 = (64 + cb0) ^ sx;
  const char* smc = (const char*)smem;

  f32x4 acc[8][4] = {};

  // prologue: t0 {A0,A1,B0,B1}, t1 {B0,B1}; retire t0, leave t1B in flight
  STAGE_HALF(Ag, 0,     0, 0, 0);
  STAGE_HALF(Ag, 0,     0, 1, 0);
  STAGE_HALF(Bg, 16384, 0, 0, 0);
  STAGE_HALF(Bg, 16384, 0, 1, 0);
  STAGE_HALF(Bg, 16384, 1, 0, 1);
  STAGE_HALF(Bg, 16384, 1, 1, 1);
  asm volatile("s_waitcnt vmcnt(4)" ::: "memory");
  __builtin_amdgcn_sched_barrier(0);
  __builtin_amdgcn_s_barrier();

  for (int t = 0; t < NT; ++t) {
    const int cur  = t & 1;
    const int curo = cur * 65536;  // byte offset of current buffer
    bf16x8 bfr[4][2];
#pragma unroll
    for (int p = 0; p < 4; ++p) {
      // --- phase p: ds-load register subtile ---
      bf16x8 af[2][2];
#pragma unroll
      for (int mi = 0; mi < 2; ++mi) {
        af[mi][0] = *(const bf16x8*)(smc + curo + arow0 + (2*p+mi)*2048 + colb0);
        af[mi][1] = *(const bf16x8*)(smc + curo + arow0 + (2*p+mi)*2048 + colb1);
      }
      if (p == 0) {
#pragma unroll
        for (int n = 0; n < 4; ++n) {
          bfr[n][0] = *(const bf16x8*)(smc + curo + brow0 + n*2048 + colb0);
          bfr[n][1] = *(const bf16x8*)(smc + curo + brow0 + n*2048 + colb1);
        }
      }
      // --- stage one half-tile (into dead region) ---
      if (p == 0 && t + 1 < NT) STAGE_HALF(Ag, 0,     t + 1, 0, cur ^ 1);
      if (p == 1 && t + 1 < NT) STAGE_HALF(Ag, 0,     t + 1, 1, cur ^ 1);
      if (p == 2 && t + 2 < NT) STAGE_HALF(Bg, 16384, t + 2, 0, cur);
      if (p == 3 && t + 2 < NT) STAGE_HALF(Bg, 16384, t + 2, 1, cur);
      __builtin_amdgcn_sched_barrier(0);
      __builtin_amdgcn_s_barrier();
      asm volatile("s_waitcnt lgkmcnt(0)" ::: "memory");
      __builtin_amdgcn_sched_barrier(0);
      // --- MFMA cluster (16) ---
      __builtin_amdgcn_s_setprio(1);
#pragma unroll
      for (int mi = 0; mi < 2; ++mi)
#pragma unroll
        for (int n = 0; n < 4; ++n) {
          acc[2*p+mi][n] = __builtin_amdgcn_mfma_f32_16x16x32_bf16(
              af[mi][0], bfr[n][0], acc[2*p+mi][n], 0, 0, 0);
          acc[2*p+mi][n] = __builtin_amdgcn_mfma_f32_16x16x32_bf16(
              af[mi][1], bfr[n][1], acc[2*p+mi][n], 0, 0, 0);
        }
      __builtin_amdgcn_s_setprio(0);
      // --- K-tile boundary: counted vmcnt (never 0 in steady state) ---
      if (p == 3) {
        if (t < NT - 2) {
          asm volatile("s_waitcnt vmcnt(4)" ::: "memory");
        } else if (t == NT - 2) {
          asm volatile("s_waitcnt vmcnt(0)" ::: "memory");
        }
        __builtin_amdgcn_sched_barrier(0);
      }
      __builtin_amdgcn_s_barrier();
    }
  }

  // ---------------- epilogue: in-lane gate fusion ----------------
  const int n_out = (bx * 4 + wc) * 16 + lr;   // hidden index 0..1023
  const float bfv = biasc[n_out];
  const float biv = biasc[1024 + n_out];
  const float bov = biasc[2048 + n_out];
  const float bcv = biasc[3072 + n_out];
  const int q0 = (lane >> 4) * 4;

#pragma unroll
  for (int m = 0; m < 8; ++m) {
    int row0 = by * 256 + wr * 128 + m * 16 + q0;
#pragma unroll
    for (int q = 0; q < 4; ++q) {
      int row = row0 + q;
      float pf = acc[m][0][q] + bfv;
      float pi = acc[m][1][q] + biv;
      float po = acc[m][2][q] + bov;
      float pc = acc[m][3][q] + bcv;
      float fg = sigmoid_f(pf);
      float ig = sigmoid_f(pi);
      float og = sigmoid_f(po);
      float cg = tanh_f(pc);
      float cold = cell[(size_t)row * NH + n_out];
      float cn = fg * cold + ig * cg;
      float hn = og * tanh_f(cn);
      outH[(size_t)row * NH + n_out] = hn;
      outC[(size_t)row * NH + n_out] = cn;
    }
  }
}

extern "C" void kernel_launch(void* const* d_in, const int* in_sizes, int n_in,
                              void* d_out, int out_size, void* d_ws, size_t ws_size,
                              hipStream_t stream) {
  const float* x    = (const float*)d_in[0];
  const float* h    = (const float*)d_in[1];
  const float* cell = (const float*)d_in[2];
  WPtrs wp; BPtrs bp;
  for (int g = 0; g < 4; ++g) {
    wp.wx[g] = (const float*)d_in[3 + 2 * g];
    bp.bx[g] = (const float*)d_in[4 + 2 * g];
    wp.wh[g] = (const float*)d_in[11 + 2 * g];
    bp.bh[g] = (const float*)d_in[12 + 2 * g];
  }

  char* ws = (char*)d_ws;
  __hip_bfloat16* Acat = (__hip_bfloat16*)ws;
  __hip_bfloat16* Bcat = (__hip_bfloat16*)(ws + (size_t)BATCH * KCAT * 2);
  float* biasc = (float*)(ws + (size_t)BATCH * KCAT * 2 + (size_t)NJ * KCAT * 2);

  float* outH = (float*)d_out;
  float* outC = outH + (size_t)BATCH * NH;

  pack_a<<<BATCH * KCAT / 8 / 256, 256, 0, stream>>>(x, h, Acat);
  pack_b<<<NJ * KCAT / 8 / 256, 256, 0, stream>>>(wp, Bcat);
  pack_bias<<<NJ / 1024 * 4, 256, 0, stream>>>(bp, biasc);

  lstm_gemm8<<<256, 512, 0, stream>>>((const unsigned short*)Acat,
                                      (const unsigned short*)Bcat,
                                      biasc, cell, outH, outC);
}

// Round 3
// 88.009 us; speedup vs baseline: 1.4617x; 1.0355x over previous
//
#include <hip/hip_runtime.h>
#include <hip/hip_bf16.h>

#define BATCH 4096
#define NH    1024
#define KCAT  2048   // x(1024) | h(1024)
#define NJ    4096   // 4 gates * 1024
#define NT    (KCAT / 64)   // 32 K-tiles

typedef __bf16 bf16x8 __attribute__((ext_vector_type(8)));
typedef float  f32x4  __attribute__((ext_vector_type(4)));
typedef unsigned short u16x8 __attribute__((ext_vector_type(8)));

struct WPtrs { const float* wx[4]; const float* wh[4]; };
struct BPtrs { const float* bx[4]; const float* bh[4]; };

__device__ __forceinline__ unsigned short f2b(float f) {
  union { float f; unsigned u; } v; v.f = f;
  return (unsigned short)((v.u + 0x7fffu + ((v.u >> 16) & 1u)) >> 16);  // RNE
}

__device__ __forceinline__ void gload_lds16(const void* g, void* l) {
  __builtin_amdgcn_global_load_lds(
      (const __attribute__((address_space(1))) unsigned int*)g,
      (__attribute__((address_space(3))) unsigned int*)l, 16, 0, 0);
}

__device__ __forceinline__ float sigmoid_f(float x) {
  x = fminf(fmaxf(x, -30.f), 30.f);
  return 1.f / (1.f + __expf(-x));
}
__device__ __forceinline__ float tanh_f(float x) {
  x = fminf(fmaxf(x, -15.f), 15.f);
  float e = __expf(2.f * x);
  return (e - 1.f) / (e + 1.f);
}

// ---------------- fused pack kernel (A-cat, B-cat, bias in one launch) -----
__global__ __launch_bounds__(256) void pack_all(
    const float* __restrict__ x, const float* __restrict__ h,
    WPtrs W, BPtrs B,
    __hip_bfloat16* __restrict__ Acat, __hip_bfloat16* __restrict__ Bcat,
    float* __restrict__ biasc) {
  int bid = blockIdx.x;
  if (bid < 4096) {            // A_cat: [row][k], k<1024 -> x, else h
    int t = bid * 256 + threadIdx.x;
    int base = t * 8;
    int row = base >> 11;
    int k   = base & 2047;
    const float* src = (k < 1024) ? (x + (size_t)row * 1024 + k)
                                  : (h + (size_t)row * 1024 + (k - 1024));
    float4 v0 = ((const float4*)src)[0];
    float4 v1 = ((const float4*)src)[1];
    u16x8 o;
    o[0]=f2b(v0.x); o[1]=f2b(v0.y); o[2]=f2b(v0.z); o[3]=f2b(v0.w);
    o[4]=f2b(v1.x); o[5]=f2b(v1.y); o[6]=f2b(v1.z); o[7]=f2b(v1.w);
    *(u16x8*)((unsigned short*)Acat + base) = o;
  } else if (bid < 8192) {     // B_cat: j = (n>>4)*64 + g*16 + (n&15)
    int t = (bid - 4096) * 256 + threadIdx.x;
    int base = t * 8;
    int j = base >> 11;
    int k = base & 2047;
    int n = ((j >> 6) << 4) + (j & 15);
    int g = (j >> 4) & 3;
    const float* src = (k < 1024) ? (W.wx[g] + (size_t)n * 1024 + k)
                                  : (W.wh[g] + (size_t)n * 1024 + (k - 1024));
    float4 v0 = ((const float4*)src)[0];
    float4 v1 = ((const float4*)src)[1];
    u16x8 o;
    o[0]=f2b(v0.x); o[1]=f2b(v0.y); o[2]=f2b(v0.z); o[3]=f2b(v0.w);
    o[4]=f2b(v1.x); o[5]=f2b(v1.y); o[6]=f2b(v1.z); o[7]=f2b(v1.w);
    *(u16x8*)((unsigned short*)Bcat + base) = o;
  } else {                     // bias: biasc[g*1024+n] = bx[g][n]+bh[g][n]
    int i = (bid - 8192) * 256 + threadIdx.x;   // 0..4095
    int g = i >> 10, n = i & 1023;
    biasc[i] = B.bx[g][n] + B.bh[g][n];
  }
}

// ---------------- 256x256 8-phase fused GEMM + LSTM epilogue ----------------
// BM=BN=256, BK=64, 8 waves (2M x 4N), per-wave 128x64 output (acc[8][4]).
// LDS 128 KiB: 2 buffers x (A 256x64 | B 256x64) bf16, XOR-swizzled
// (LDS[row][c16] = G[row][c16 ^ (row&7)], read col byte ^= (row&7)<<4).
// DEEP stagger (all waits 4-7 phases after issue; vmcnt(7) steady state):
//   tile t phase 0: stage A-slice3(t+1)            (into buf cur^1; dead rows)
//   tile t phase 1: stage A-slice0(t+2) + B-half0(t+2)  (buf cur; consumed rows,
//   tile t phase 2: stage A-slice1(t+2) + B-half1(t+2)   B dead after phase 0)
//   tile t phase 3: stage A-slice2(t+2)
// A-slice S = rows {S*32..+32} u {128+S*32..+32} (consumed at phase S).
// Boundary vmcnt(7) retires exactly A(t+1)+B(t+1)'s 8 loads.

#define STAGE_A_HALF(T, H)                                                      \
  {                                                                             \
    _Pragma("unroll")                                                           \
    for (int i_ = 0; i_ < 2; ++i_) {                                            \
      gload_lds16(Ag + (size_t)((H)*128 + i_*64 + strow) * KCAT + (T)*64 +      \
                      stchnk * 8,                                               \
                  &smem[((T)&1)*32768 + (H)*8192 + i_*4096 + w*512]);           \
    }                                                                           \
  }
#define STAGE_B_HALF(T, H)                                                      \
  {                                                                             \
    _Pragma("unroll")                                                           \
    for (int i_ = 0; i_ < 2; ++i_) {                                            \
      gload_lds16(Bg + (size_t)((H)*128 + i_*64 + strow) * KCAT + (T)*64 +      \
                      stchnk * 8,                                               \
                  &smem[((T)&1)*32768 + 16384 + (H)*8192 + i_*4096 + w*512]);   \
    }                                                                           \
  }
#define STAGE_A_SLICE(T, S)                                                     \
  {                                                                             \
    gload_lds16(Ag + (size_t)(arbw + (S)*32 + (lane >> 3)) * KCAT + (T)*64 +    \
                    stchnk * 8,                                                 \
                &smem[((T)&1)*32768 + (arbw + (S)*32) * 64]);                   \
  }

__global__ __launch_bounds__(512, 2) void lstm_gemm8(
    const unsigned short* __restrict__ Acat,
    const unsigned short* __restrict__ Bcat,
    const float* __restrict__ biasc,
    const float* __restrict__ cell,
    float* __restrict__ outH, float* __restrict__ outC) {
  __shared__ unsigned short smem[65536];  // 128 KiB

  const int tid  = threadIdx.x;
  const int w    = tid >> 6;    // 0..7
  const int lane = tid & 63;
  const int wr   = w >> 2;      // 0..1 (M)
  const int wc   = w & 3;       // 0..3 (N)
  const int lr   = lane & 15;
  const int cb0  = ((lane >> 4) & 3) * 16;   // 16B chunk within row
  const int sx   = (lr & 7) << 4;            // read-side swizzle XOR

  // XCD-aware bijective swizzle (256 blocks, 8 XCDs)
  const int bid = blockIdx.x;
  const int s   = (bid & 7) * 32 + (bid >> 3);
  const int bx  = s & 15;
  const int by  = s >> 4;

  const unsigned short* Ag = Acat + (size_t)(by * 256) * KCAT;
  const unsigned short* Bg = Bcat + (size_t)(bx * 256) * KCAT;

  // staging source mapping (pre-swizzled global chunk)
  const int strow  = w * 8 + (lane >> 3);              // row within 128-row half
  const int stchnk = (lane & 7) ^ ((lane >> 3) & 7);   // swizzled src chunk
  const int arbw   = (w >> 2) * 128 + (w & 3) * 8;     // wave's slice row base

  // per-thread read base byte offsets into smem
  const int arow0 = (wr * 128 + lr) * 128;          // + m*2048 + colb
  const int brow0 = 32768 + (wc * 64 + lr) * 128;   // + n*2048 + colb
  const int colb0 = cb0 ^ sx;
  const int colb1 = (64 + cb0) ^ sx;
  const char* smc = (const char*)smem;

  // hoist epilogue scalars (covered by K-loop)
  const int n_out = (bx * 4 + wc) * 16 + lr;   // hidden index 0..1023
  const float bfv = biasc[n_out];
  const float biv = biasc[1024 + n_out];
  const float bov = biasc[2048 + n_out];
  const float bcv = biasc[3072 + n_out];

  f32x4 acc[8][4] = {};

  // prologue: tile0 fully, tile1 A-slices 0-2 + B halves; wait tile0 (vmcnt 7)
  STAGE_A_HALF(0, 0);
  STAGE_A_HALF(0, 1);
  STAGE_B_HALF(0, 0);
  STAGE_B_HALF(0, 1);
  STAGE_A_SLICE(1, 0);
  STAGE_A_SLICE(1, 1);
  STAGE_A_SLICE(1, 2);
  STAGE_B_HALF(1, 0);
  STAGE_B_HALF(1, 1);
  asm volatile("s_waitcnt vmcnt(7)" ::: "memory");
  __builtin_amdgcn_sched_barrier(0);
  __builtin_amdgcn_s_barrier();

  for (int t = 0; t < NT; ++t) {
    const int cur  = t & 1;
    const int curo = cur * 65536;  // byte offset of current buffer
    bf16x8 bfr[4][2];
#pragma unroll
    for (int p = 0; p < 4; ++p) {
      // --- ds-load register subtile ---
      bf16x8 af[2][2];
#pragma unroll
      for (int mi = 0; mi < 2; ++mi) {
        af[mi][0] = *(const bf16x8*)(smc + curo + arow0 + (2*p+mi)*2048 + colb0);
        af[mi][1] = *(const bf16x8*)(smc + curo + arow0 + (2*p+mi)*2048 + colb1);
      }
      if (p == 0) {
#pragma unroll
        for (int n = 0; n < 4; ++n) {
          bfr[n][0] = *(const bf16x8*)(smc + curo + brow0 + n*2048 + colb0);
          bfr[n][1] = *(const bf16x8*)(smc + curo + brow0 + n*2048 + colb1);
        }
      }
      // --- deep-stagger staging (each target region is dead) ---
      if (p == 0 && t + 1 < NT) STAGE_A_SLICE(t + 1, 3);
      if (p == 1 && t + 2 < NT) { STAGE_A_SLICE(t + 2, 0); STAGE_B_HALF(t + 2, 0); }
      if (p == 2 && t + 2 < NT) { STAGE_A_SLICE(t + 2, 1); STAGE_B_HALF(t + 2, 1); }
      if (p == 3 && t + 2 < NT) STAGE_A_SLICE(t + 2, 2);
      if (p == 0) asm volatile("s_waitcnt lgkmcnt(8)" ::: "memory");
      __builtin_amdgcn_sched_barrier(0);
      __builtin_amdgcn_s_barrier();
      asm volatile("s_waitcnt lgkmcnt(0)" ::: "memory");
      __builtin_amdgcn_sched_barrier(0);
      // --- MFMA cluster (16) ---
      __builtin_amdgcn_s_setprio(1);
#pragma unroll
      for (int mi = 0; mi < 2; ++mi)
#pragma unroll
        for (int n = 0; n < 4; ++n) {
          acc[2*p+mi][n] = __builtin_amdgcn_mfma_f32_16x16x32_bf16(
              af[mi][0], bfr[n][0], acc[2*p+mi][n], 0, 0, 0);
          acc[2*p+mi][n] = __builtin_amdgcn_mfma_f32_16x16x32_bf16(
              af[mi][1], bfr[n][1], acc[2*p+mi][n], 0, 0, 0);
        }
      __builtin_amdgcn_s_setprio(0);
      // --- K-tile boundary: counted vmcnt (never 0 in steady state) ---
      if (p == 3) {
        if (t < NT - 2) {
          asm volatile("s_waitcnt vmcnt(7)" ::: "memory");
        } else if (t == NT - 2) {
          asm volatile("s_waitcnt vmcnt(0)" ::: "memory");
        }
        __builtin_amdgcn_sched_barrier(0);
      }
      __builtin_amdgcn_s_barrier();
    }
  }

  // ---------------- epilogue: in-lane gate fusion ----------------
  const int q0 = (lane >> 4) * 4;
#pragma unroll
  for (int m = 0; m < 8; ++m) {
    int row0 = by * 256 + wr * 128 + m * 16 + q0;
#pragma unroll
    for (int q = 0; q < 4; ++q) {
      int row = row0 + q;
      float pf = acc[m][0][q] + bfv;
      float pi = acc[m][1][q] + biv;
      float po = acc[m][2][q] + bov;
      float pc = acc[m][3][q] + bcv;
      float fg = sigmoid_f(pf);
      float ig = sigmoid_f(pi);
      float og = sigmoid_f(po);
      float cg = tanh_f(pc);
      float cold = cell[(size_t)row * NH + n_out];
      float cn = fg * cold + ig * cg;
      float hn = og * tanh_f(cn);
      outH[(size_t)row * NH + n_out] = hn;
      outC[(size_t)row * NH + n_out] = cn;
    }
  }
}

extern "C" void kernel_launch(void* const* d_in, const int* in_sizes, int n_in,
                              void* d_out, int out_size, void* d_ws, size_t ws_size,
                              hipStream_t stream) {
  const float* x    = (const float*)d_in[0];
  const float* h    = (const float*)d_in[1];
  const float* cell = (const float*)d_in[2];
  WPtrs wp; BPtrs bp;
  for (int g = 0; g < 4; ++g) {
    wp.wx[g] = (const float*)d_in[3 + 2 * g];
    bp.bx[g] = (const float*)d_in[4 + 2 * g];
    wp.wh[g] = (const float*)d_in[11 + 2 * g];
    bp.bh[g] = (const float*)d_in[12 + 2 * g];
  }

  char* ws = (char*)d_ws;
  __hip_bfloat16* Acat = (__hip_bfloat16*)ws;
  __hip_bfloat16* Bcat = (__hip_bfloat16*)(ws + (size_t)BATCH * KCAT * 2);
  float* biasc = (float*)(ws + (size_t)BATCH * KCAT * 2 + (size_t)NJ * KCAT * 2);

  float* outH = (float*)d_out;
  float* outC = outH + (size_t)BATCH * NH;

  pack_all<<<8208, 256, 0, stream>>>(x, h, wp, bp, Acat, Bcat, biasc);

  lstm_gemm8<<<256, 512, 0, stream>>>((const unsigned short*)Acat,
                                      (const unsigned short*)Bcat,
                                      biasc, cell, outH, outC);
}

// Round 4
// 87.558 us; speedup vs baseline: 1.4692x; 1.0051x over previous
//
#include <hip/hip_runtime.h>
#include <hip/hip_bf16.h>

#define BATCH 4096
#define NH    1024
#define KCAT  2048   // x(1024) | h(1024)
#define NJ    4096   // 4 gates * 1024
#define NT    (KCAT / 64)   // 32 K-tiles

typedef __bf16 bf16x8 __attribute__((ext_vector_type(8)));
typedef float  f32x4  __attribute__((ext_vector_type(4)));
typedef unsigned short u16x8 __attribute__((ext_vector_type(8)));

struct WPtrs { const float* wx[4]; const float* wh[4]; };
struct BPtrs { const float* bx[4]; const float* bh[4]; };

__device__ __forceinline__ unsigned short f2b(float f) {
  union { float f; unsigned u; } v; v.f = f;
  return (unsigned short)((v.u + 0x7fffu + ((v.u >> 16) & 1u)) >> 16);  // RNE
}

__device__ __forceinline__ void gload_lds16(const void* g, void* l) {
  __builtin_amdgcn_global_load_lds(
      (const __attribute__((address_space(1))) unsigned int*)g,
      (__attribute__((address_space(3))) unsigned int*)l, 16, 0, 0);
}

__device__ __forceinline__ float sigmoid_f(float x) {
  x = fminf(fmaxf(x, -30.f), 30.f);
  return 1.f / (1.f + __expf(-x));
}
__device__ __forceinline__ float tanh_f(float x) {
  x = fminf(fmaxf(x, -15.f), 15.f);
  float e = __expf(2.f * x);
  return (e - 1.f) / (e + 1.f);
}

// ---------------- fused pack kernel (A-cat, B-cat, bias in one launch) -----
__global__ __launch_bounds__(256) void pack_all(
    const float* __restrict__ x, const float* __restrict__ h,
    WPtrs W, BPtrs B,
    __hip_bfloat16* __restrict__ Acat, __hip_bfloat16* __restrict__ Bcat,
    float* __restrict__ biasc) {
  int bid = blockIdx.x;
  if (bid < 4096) {            // A_cat: [row][k], k<1024 -> x, else h
    int t = bid * 256 + threadIdx.x;
    int base = t * 8;
    int row = base >> 11;
    int k   = base & 2047;
    const float* src = (k < 1024) ? (x + (size_t)row * 1024 + k)
                                  : (h + (size_t)row * 1024 + (k - 1024));
    float4 v0 = ((const float4*)src)[0];
    float4 v1 = ((const float4*)src)[1];
    u16x8 o;
    o[0]=f2b(v0.x); o[1]=f2b(v0.y); o[2]=f2b(v0.z); o[3]=f2b(v0.w);
    o[4]=f2b(v1.x); o[5]=f2b(v1.y); o[6]=f2b(v1.z); o[7]=f2b(v1.w);
    *(u16x8*)((unsigned short*)Acat + base) = o;
  } else if (bid < 8192) {     // B_cat: j = (n>>4)*64 + g*16 + (n&15)
    int t = (bid - 4096) * 256 + threadIdx.x;
    int base = t * 8;
    int j = base >> 11;
    int k = base & 2047;
    int n = ((j >> 6) << 4) + (j & 15);
    int g = (j >> 4) & 3;
    const float* src = (k < 1024) ? (W.wx[g] + (size_t)n * 1024 + k)
                                  : (W.wh[g] + (size_t)n * 1024 + (k - 1024));
    float4 v0 = ((const float4*)src)[0];
    float4 v1 = ((const float4*)src)[1];
    u16x8 o;
    o[0]=f2b(v0.x); o[1]=f2b(v0.y); o[2]=f2b(v0.z); o[3]=f2b(v0.w);
    o[4]=f2b(v1.x); o[5]=f2b(v1.y); o[6]=f2b(v1.z); o[7]=f2b(v1.w);
    *(u16x8*)((unsigned short*)Bcat + base) = o;
  } else {                     // bias: biasc[g*1024+n] = bx[g][n]+bh[g][n]
    int i = (bid - 8192) * 256 + threadIdx.x;   // 0..4095
    int g = i >> 10, n = i & 1023;
    biasc[i] = B.bx[g][n] + B.bh[g][n];
  }
}

// ---------------- 256x256 8-phase fused GEMM + LSTM epilogue ----------------
// As r3 (deep stagger, XOR swizzle, 0 conflicts) PLUS 1-phase-deep A-fragment
// register double-buffer: phase p issues phase p+1's 4 ds_reads before p's
// MFMA cluster; MFMA waits counted lgkmcnt(4) instead of lgkmcnt(0).
// Cross-tile prefetch (p3 -> next p0) goes AFTER the mid-phase barrier
// (cross-wave staged data guaranteed only by per-wave vmcnt + barrier);
// boundary vmcnt moves to p3-start as vmcnt(6) (retires all of tile t+1).

#define STAGE_A_HALF(T, H)                                                      \
  {                                                                             \
    _Pragma("unroll")                                                           \
    for (int i_ = 0; i_ < 2; ++i_) {                                            \
      gload_lds16(Ag + (size_t)((H)*128 + i_*64 + strow) * KCAT + (T)*64 +      \
                      stchnk * 8,                                               \
                  &smem[((T)&1)*32768 + (H)*8192 + i_*4096 + w*512]);           \
    }                                                                           \
  }
#define STAGE_B_HALF(T, H)                                                      \
  {                                                                             \
    _Pragma("unroll")                                                           \
    for (int i_ = 0; i_ < 2; ++i_) {                                            \
      gload_lds16(Bg + (size_t)((H)*128 + i_*64 + strow) * KCAT + (T)*64 +      \
                      stchnk * 8,                                               \
                  &smem[((T)&1)*32768 + 16384 + (H)*8192 + i_*4096 + w*512]);   \
    }                                                                           \
  }
#define STAGE_A_SLICE(T, S)                                                     \
  {                                                                             \
    gload_lds16(Ag + (size_t)(arbw + (S)*32 + (lane >> 3)) * KCAT + (T)*64 +    \
                    stchnk * 8,                                                 \
                &smem[((T)&1)*32768 + (arbw + (S)*32) * 64]);                   \
  }

#define LDA_(BUFO, MP, KH)                                                      \
  (*(const bf16x8*)(smc + (BUFO) + arow0 + (MP)*2048 + ((KH) ? colb1 : colb0)))
#define LDB_(BUFO, N, KH)                                                       \
  (*(const bf16x8*)(smc + (BUFO) + brow0 + (N)*2048 + ((KH) ? colb1 : colb0)))

__global__ __launch_bounds__(512, 2) void lstm_gemm8(
    const unsigned short* __restrict__ Acat,
    const unsigned short* __restrict__ Bcat,
    const float* __restrict__ biasc,
    const float* __restrict__ cell,
    float* __restrict__ outH, float* __restrict__ outC) {
  __shared__ unsigned short smem[65536];  // 128 KiB

  const int tid  = threadIdx.x;
  const int w    = tid >> 6;    // 0..7
  const int lane = tid & 63;
  const int wr   = w >> 2;      // 0..1 (M)
  const int wc   = w & 3;       // 0..3 (N)
  const int lr   = lane & 15;
  const int cb0  = ((lane >> 4) & 3) * 16;   // 16B chunk within row
  const int sx   = (lr & 7) << 4;            // read-side swizzle XOR

  // XCD-aware bijective swizzle (256 blocks, 8 XCDs)
  const int bid = blockIdx.x;
  const int s   = (bid & 7) * 32 + (bid >> 3);
  const int bx  = s & 15;
  const int by  = s >> 4;

  const unsigned short* Ag = Acat + (size_t)(by * 256) * KCAT;
  const unsigned short* Bg = Bcat + (size_t)(bx * 256) * KCAT;

  // staging source mapping (pre-swizzled global chunk)
  const int strow  = w * 8 + (lane >> 3);              // row within 128-row half
  const int stchnk = (lane & 7) ^ ((lane >> 3) & 7);   // swizzled src chunk
  const int arbw   = (w >> 2) * 128 + (w & 3) * 8;     // wave's slice row base

  // per-thread read base byte offsets into smem
  const int arow0 = (wr * 128 + lr) * 128;          // + m*2048 + colb
  const int brow0 = 32768 + (wc * 64 + lr) * 128;   // + n*2048 + colb
  const int colb0 = cb0 ^ sx;
  const int colb1 = (64 + cb0) ^ sx;
  const char* smc = (const char*)smem;

  f32x4 acc[8][4] = {};
  bf16x8 af[2][2][2];   // [parity][mi][khalf] — ping-pong A fragments
  bf16x8 bfr[4][2];

  // prologue: tile0 fully, tile1 A-slices 0-2 + B halves; wait tile0 (vmcnt 7)
  STAGE_A_HALF(0, 0);
  STAGE_A_HALF(0, 1);
  STAGE_B_HALF(0, 0);
  STAGE_B_HALF(0, 1);
  STAGE_A_SLICE(1, 0);
  STAGE_A_SLICE(1, 1);
  STAGE_A_SLICE(1, 2);
  STAGE_B_HALF(1, 0);
  STAGE_B_HALF(1, 1);
  asm volatile("s_waitcnt vmcnt(7)" ::: "memory");
  __builtin_amdgcn_sched_barrier(0);
  __builtin_amdgcn_s_barrier();
  // preload af for (t0, p0) — safe after barrier
#pragma unroll
  for (int mi = 0; mi < 2; ++mi) {
    af[0][mi][0] = LDA_(0, mi, 0);
    af[0][mi][1] = LDA_(0, mi, 1);
  }

  for (int t = 0; t < NT; ++t) {
    const int curo = (t & 1) * 65536;  // byte offset of current buffer
    const int nxto = curo ^ 65536;
#pragma unroll
    for (int p = 0; p < 4; ++p) {
      const int cs = p & 1;       // current af set (compile-time after unroll)
      const int ns = cs ^ 1;
      // --- p0: load B fragments for whole tile (8 ds_reads) ---
      if (p == 0) {
#pragma unroll
        for (int n = 0; n < 4; ++n) {
          bfr[n][0] = LDB_(curo, n, 0);
          bfr[n][1] = LDB_(curo, n, 1);
        }
      }
      // --- same-tile af prefetch for phase p+1 (p = 0..2) ---
      if (p < 3) {
#pragma unroll
        for (int mi = 0; mi < 2; ++mi) {
          af[ns][mi][0] = LDA_(curo, 2*(p+1)+mi, 0);
          af[ns][mi][1] = LDA_(curo, 2*(p+1)+mi, 1);
        }
      }
      // --- deep-stagger staging (each target region is dead) ---
      if (p == 0 && t + 1 < NT) STAGE_A_SLICE(t + 1, 3);
      if (p == 1 && t + 2 < NT) { STAGE_A_SLICE(t + 2, 0); STAGE_B_HALF(t + 2, 0); }
      if (p == 2 && t + 2 < NT) { STAGE_A_SLICE(t + 2, 1); STAGE_B_HALF(t + 2, 1); }
      if (p == 3) {
        // boundary: retire ALL of tile t+1 BEFORE staging/prefetching
        if (t < NT - 2) {
          asm volatile("s_waitcnt vmcnt(6)" ::: "memory");
        } else if (t == NT - 2) {
          asm volatile("s_waitcnt vmcnt(0)" ::: "memory");
        }
        __builtin_amdgcn_sched_barrier(0);
        if (t + 2 < NT) STAGE_A_SLICE(t + 2, 2);
      }
      __builtin_amdgcn_sched_barrier(0);
      __builtin_amdgcn_s_barrier();
      // --- p3: cross-tile af prefetch (next tile p0) — post-barrier only ---
      if (p == 3) {
        if (t + 1 < NT) {
#pragma unroll
          for (int mi = 0; mi < 2; ++mi) {
            af[ns][mi][0] = LDA_(nxto, mi, 0);
            af[ns][mi][1] = LDA_(nxto, mi, 1);
          }
          asm volatile("s_waitcnt lgkmcnt(4)" ::: "memory");
        } else {
          asm volatile("s_waitcnt lgkmcnt(0)" ::: "memory");
        }
      } else {
        asm volatile("s_waitcnt lgkmcnt(4)" ::: "memory");
      }
      __builtin_amdgcn_sched_barrier(0);
      // --- MFMA cluster (16) on af[cs] (loaded LAST phase) ---
      __builtin_amdgcn_s_setprio(1);
#pragma unroll
      for (int mi = 0; mi < 2; ++mi)
#pragma unroll
        for (int n = 0; n < 4; ++n) {
          acc[2*p+mi][n] = __builtin_amdgcn_mfma_f32_16x16x32_bf16(
              af[cs][mi][0], bfr[n][0], acc[2*p+mi][n], 0, 0, 0);
          acc[2*p+mi][n] = __builtin_amdgcn_mfma_f32_16x16x32_bf16(
              af[cs][mi][1], bfr[n][1], acc[2*p+mi][n], 0, 0, 0);
        }
      __builtin_amdgcn_s_setprio(0);
      __builtin_amdgcn_s_barrier();
    }
  }

  // ---------------- epilogue: in-lane gate fusion ----------------
  const int n_out = (bx * 4 + wc) * 16 + lr;   // hidden index 0..1023
  const float bfv = biasc[n_out];
  const float biv = biasc[1024 + n_out];
  const float bov = biasc[2048 + n_out];
  const float bcv = biasc[3072 + n_out];
  const int q0 = (lane >> 4) * 4;

#pragma unroll
  for (int m = 0; m < 8; ++m) {
    int row0 = by * 256 + wr * 128 + m * 16 + q0;
#pragma unroll
    for (int q = 0; q < 4; ++q) {
      int row = row0 + q;
      float pf = acc[m][0][q] + bfv;
      float pi = acc[m][1][q] + biv;
      float po = acc[m][2][q] + bov;
      float pc = acc[m][3][q] + bcv;
      float fg = sigmoid_f(pf);
      float ig = sigmoid_f(pi);
      float og = sigmoid_f(po);
      float cg = tanh_f(pc);
      float cold = cell[(size_t)row * NH + n_out];
      float cn = fg * cold + ig * cg;
      float hn = og * tanh_f(cn);
      outH[(size_t)row * NH + n_out] = hn;
      outC[(size_t)row * NH + n_out] = cn;
    }
  }
}

extern "C" void kernel_launch(void* const* d_in, const int* in_sizes, int n_in,
                              void* d_out, int out_size, void* d_ws, size_t ws_size,
                              hipStream_t stream) {
  const float* x    = (const float*)d_in[0];
  const float* h    = (const float*)d_in[1];
  const float* cell = (const float*)d_in[2];
  WPtrs wp; BPtrs bp;
  for (int g = 0; g < 4; ++g) {
    wp.wx[g] = (const float*)d_in[3 + 2 * g];
    bp.bx[g] = (const float*)d_in[4 + 2 * g];
    wp.wh[g] = (const float*)d_in[11 + 2 * g];
    bp.bh[g] = (const float*)d_in[12 + 2 * g];
  }

  char* ws = (char*)d_ws;
  __hip_bfloat16* Acat = (__hip_bfloat16*)ws;
  __hip_bfloat16* Bcat = (__hip_bfloat16*)(ws + (size_t)BATCH * KCAT * 2);
  float* biasc = (float*)(ws + (size_t)BATCH * KCAT * 2 + (size_t)NJ * KCAT * 2);

  float* outH = (float*)d_out;
  float* outC = outH + (size_t)BATCH * NH;

  pack_all<<<8208, 256, 0, stream>>>(x, h, wp, bp, Acat, Bcat, biasc);

  lstm_gemm8<<<256, 512, 0, stream>>>((const unsigned short*)Acat,
                                      (const unsigned short*)Bcat,
                                      biasc, cell, outH, outC);
}

// Round 5
// 85.932 us; speedup vs baseline: 1.4970x; 1.0189x over previous
//
#include <hip/hip_runtime.h>
#include <hip/hip_bf16.h>

#define BATCH 4096
#define NH    1024
#define KCAT  2048   // x(1024) | h(1024)
#define NJ    4096   // 4 gates * 1024
#define NT    (KCAT / 64)   // 32 K-tiles

typedef __bf16 bf16x8 __attribute__((ext_vector_type(8)));
typedef float  f32x4  __attribute__((ext_vector_type(4)));
typedef unsigned short u16x8 __attribute__((ext_vector_type(8)));

struct WPtrs { const float* wx[4]; const float* wh[4]; };
struct BPtrs { const float* bx[4]; const float* bh[4]; };

__device__ __forceinline__ unsigned short f2b(float f) {
  union { float f; unsigned u; } v; v.f = f;
  return (unsigned short)((v.u + 0x7fffu + ((v.u >> 16) & 1u)) >> 16);  // RNE
}

__device__ __forceinline__ void gload_lds16(const void* g, void* l) {
  __builtin_amdgcn_global_load_lds(
      (const __attribute__((address_space(1))) unsigned int*)g,
      (__attribute__((address_space(3))) unsigned int*)l, 16, 0, 0);
}

__device__ __forceinline__ float sigmoid_f(float x) {
  x = fminf(fmaxf(x, -30.f), 30.f);
  return 1.f / (1.f + __expf(-x));
}
__device__ __forceinline__ float tanh_f(float x) {
  x = fminf(fmaxf(x, -15.f), 15.f);
  float e = __expf(2.f * x);
  return (e - 1.f) / (e + 1.f);
}

// ---------------- fused pack kernel (A-cat, B-cat, bias in one launch) -----
__global__ __launch_bounds__(256) void pack_all(
    const float* __restrict__ x, const float* __restrict__ h,
    WPtrs W, BPtrs B,
    __hip_bfloat16* __restrict__ Acat, __hip_bfloat16* __restrict__ Bcat,
    float* __restrict__ biasc) {
  int bid = blockIdx.x;
  if (bid < 4096) {            // A_cat: [row][k], k<1024 -> x, else h
    int t = bid * 256 + threadIdx.x;
    int base = t * 8;
    int row = base >> 11;
    int k   = base & 2047;
    const float* src = (k < 1024) ? (x + (size_t)row * 1024 + k)
                                  : (h + (size_t)row * 1024 + (k - 1024));
    float4 v0 = ((const float4*)src)[0];
    float4 v1 = ((const float4*)src)[1];
    u16x8 o;
    o[0]=f2b(v0.x); o[1]=f2b(v0.y); o[2]=f2b(v0.z); o[3]=f2b(v0.w);
    o[4]=f2b(v1.x); o[5]=f2b(v1.y); o[6]=f2b(v1.z); o[7]=f2b(v1.w);
    *(u16x8*)((unsigned short*)Acat + base) = o;
  } else if (bid < 8192) {     // B_cat: j = (n>>4)*64 + g*16 + (n&15)
    int t = (bid - 4096) * 256 + threadIdx.x;
    int base = t * 8;
    int j = base >> 11;
    int k = base & 2047;
    int n = ((j >> 6) << 4) + (j & 15);
    int g = (j >> 4) & 3;
    const float* src = (k < 1024) ? (W.wx[g] + (size_t)n * 1024 + k)
                                  : (W.wh[g] + (size_t)n * 1024 + (k - 1024));
    float4 v0 = ((const float4*)src)[0];
    float4 v1 = ((const float4*)src)[1];
    u16x8 o;
    o[0]=f2b(v0.x); o[1]=f2b(v0.y); o[2]=f2b(v0.z); o[3]=f2b(v0.w);
    o[4]=f2b(v1.x); o[5]=f2b(v1.y); o[6]=f2b(v1.z); o[7]=f2b(v1.w);
    *(u16x8*)((unsigned short*)Bcat + base) = o;
  } else {                     // bias: biasc[g*1024+n] = bx[g][n]+bh[g][n]
    int i = (bid - 8192) * 256 + threadIdx.x;   // 0..4095
    int g = i >> 10, n = i & 1023;
    biasc[i] = B.bx[g][n] + B.bh[g][n];
  }
}

// ---------------- 256x256 thin-sync 8-phase GEMM + LSTM epilogue -----------
// vs r4: ONE barrier per phase (4/tile, was 8); graded group-lgkmcnt at p0 so
// 8 MFMAs overlap the B-drain; kh-outer MFMA order (same-acc RAW distance 8).
// Hazards: every stage targets a region whose last reader issued >=1
// end-of-phase barrier earlier; tile t+1 data published by p3's vmcnt(6)
// (retires exactly tile t+1's 8 loads; steady-state 14 in flight) + p3-end
// barrier. Read-group order pinned by sched_barrier(0); lgkmcnt counts are
// group-granular (DS ops retire in order per wave).

#define STAGE_A_HALF(T, H)                                                      \
  {                                                                             \
    _Pragma("unroll")                                                           \
    for (int i_ = 0; i_ < 2; ++i_) {                                            \
      gload_lds16(Ag + (size_t)((H)*128 + i_*64 + strow) * KCAT + (T)*64 +      \
                      stchnk * 8,                                               \
                  &smem[((T)&1)*32768 + (H)*8192 + i_*4096 + w*512]);           \
    }                                                                           \
  }
#define STAGE_B_HALF(T, H)                                                      \
  {                                                                             \
    _Pragma("unroll")                                                           \
    for (int i_ = 0; i_ < 2; ++i_) {                                            \
      gload_lds16(Bg + (size_t)((H)*128 + i_*64 + strow) * KCAT + (T)*64 +      \
                      stchnk * 8,                                               \
                  &smem[((T)&1)*32768 + 16384 + (H)*8192 + i_*4096 + w*512]);   \
    }                                                                           \
  }
#define STAGE_A_SLICE(T, S)                                                     \
  {                                                                             \
    gload_lds16(Ag + (size_t)(arbw + (S)*32 + (lane >> 3)) * KCAT + (T)*64 +    \
                    stchnk * 8,                                                 \
                &smem[((T)&1)*32768 + (arbw + (S)*32) * 64]);                   \
  }

#define LDA_(BUFO, MP, KH)                                                      \
  (*(const bf16x8*)(smc + (BUFO) + arow0 + (MP)*2048 + ((KH) ? colb1 : colb0)))
#define LDB_(BUFO, N, KH)                                                       \
  (*(const bf16x8*)(smc + (BUFO) + brow0 + (N)*2048 + ((KH) ? colb1 : colb0)))

// 8 MFMAs: one k-half, acc rows BASE,BASE+1, af set SET
#define MFMA_HALF(BASE, SET, KH)                                                \
  {                                                                             \
    _Pragma("unroll")                                                           \
    for (int mi_ = 0; mi_ < 2; ++mi_)                                           \
      _Pragma("unroll")                                                         \
      for (int n_ = 0; n_ < 4; ++n_)                                            \
        acc[(BASE)+mi_][n_] = __builtin_amdgcn_mfma_f32_16x16x32_bf16(          \
            af[SET][mi_][KH], bfr[n_][KH], acc[(BASE)+mi_][n_], 0, 0, 0);       \
  }

__global__ __launch_bounds__(512, 2) void lstm_gemm8(
    const unsigned short* __restrict__ Acat,
    const unsigned short* __restrict__ Bcat,
    const float* __restrict__ biasc,
    const float* __restrict__ cell,
    float* __restrict__ outH, float* __restrict__ outC) {
  __shared__ unsigned short smem[65536];  // 128 KiB

  const int tid  = threadIdx.x;
  const int w    = tid >> 6;    // 0..7
  const int lane = tid & 63;
  const int wr   = w >> 2;      // 0..1 (M)
  const int wc   = w & 3;       // 0..3 (N)
  const int lr   = lane & 15;
  const int cb0  = ((lane >> 4) & 3) * 16;   // 16B chunk within row
  const int sx   = (lr & 7) << 4;            // read-side swizzle XOR

  // XCD-aware bijective swizzle (256 blocks, 8 XCDs)
  const int bid = blockIdx.x;
  const int s   = (bid & 7) * 32 + (bid >> 3);
  const int bx  = s & 15;
  const int by  = s >> 4;

  const unsigned short* Ag = Acat + (size_t)(by * 256) * KCAT;
  const unsigned short* Bg = Bcat + (size_t)(bx * 256) * KCAT;

  // staging source mapping (pre-swizzled global chunk)
  const int strow  = w * 8 + (lane >> 3);              // row within 128-row half
  const int stchnk = (lane & 7) ^ ((lane >> 3) & 7);   // swizzled src chunk
  const int arbw   = (w >> 2) * 128 + (w & 3) * 8;     // wave's slice row base

  // per-thread read base byte offsets into smem
  const int arow0 = (wr * 128 + lr) * 128;          // + m*2048 + colb
  const int brow0 = 32768 + (wc * 64 + lr) * 128;   // + n*2048 + colb
  const int colb0 = cb0 ^ sx;
  const int colb1 = (64 + cb0) ^ sx;
  const char* smc = (const char*)smem;

  f32x4 acc[8][4] = {};
  bf16x8 af[2][2][2];   // [set][mi][khalf]
  bf16x8 bfr[4][2];

  // prologue: tile0 fully, tile1 A-slices 0-2 + B halves; wait tile0 (vmcnt 7)
  STAGE_A_HALF(0, 0);
  STAGE_A_HALF(0, 1);
  STAGE_B_HALF(0, 0);
  STAGE_B_HALF(0, 1);
  STAGE_A_SLICE(1, 0);
  STAGE_A_SLICE(1, 1);
  STAGE_A_SLICE(1, 2);
  STAGE_B_HALF(1, 0);
  STAGE_B_HALF(1, 1);
  asm volatile("s_waitcnt vmcnt(7)" ::: "memory");
  __builtin_amdgcn_sched_barrier(0);
  __builtin_amdgcn_s_barrier();

  for (int t = 0; t < NT; ++t) {
    const int curo = (t & 1) * 65536;  // byte offset of current buffer

    // ---------------- phase 0 (acc rows 0,1; af set 0) ----------------
    // pinned lgkm groups: [af p0 x4][B kh0 x4][B kh1 x4][af p1 x4]
    af[0][0][0] = LDA_(curo, 0, 0); af[0][0][1] = LDA_(curo, 0, 1);
    af[0][1][0] = LDA_(curo, 1, 0); af[0][1][1] = LDA_(curo, 1, 1);
    __builtin_amdgcn_sched_barrier(0);
    bfr[0][0] = LDB_(curo, 0, 0); bfr[1][0] = LDB_(curo, 1, 0);
    bfr[2][0] = LDB_(curo, 2, 0); bfr[3][0] = LDB_(curo, 3, 0);
    __builtin_amdgcn_sched_barrier(0);
    bfr[0][1] = LDB_(curo, 0, 1); bfr[1][1] = LDB_(curo, 1, 1);
    bfr[2][1] = LDB_(curo, 2, 1); bfr[3][1] = LDB_(curo, 3, 1);
    __builtin_amdgcn_sched_barrier(0);
    if (t + 1 < NT) STAGE_A_SLICE(t + 1, 3);
    af[1][0][0] = LDA_(curo, 2, 0); af[1][0][1] = LDA_(curo, 2, 1);
    af[1][1][0] = LDA_(curo, 3, 0); af[1][1][1] = LDA_(curo, 3, 1);
    __builtin_amdgcn_sched_barrier(0);
    __builtin_amdgcn_s_setprio(1);
    asm volatile("s_waitcnt lgkmcnt(8)" ::: "memory");   // af p0 + B kh0 done
    __builtin_amdgcn_sched_barrier(0);
    MFMA_HALF(0, 0, 0);
    asm volatile("s_waitcnt lgkmcnt(4)" ::: "memory");   // + B kh1 done
    __builtin_amdgcn_sched_barrier(0);
    MFMA_HALF(0, 0, 1);
    __builtin_amdgcn_s_setprio(0);
    __builtin_amdgcn_s_barrier();

    // ---------------- phase 1 (acc rows 2,3; af set 1) ----------------
    af[0][0][0] = LDA_(curo, 4, 0); af[0][0][1] = LDA_(curo, 4, 1);
    af[0][1][0] = LDA_(curo, 5, 0); af[0][1][1] = LDA_(curo, 5, 1);
    __builtin_amdgcn_sched_barrier(0);
    if (t + 2 < NT) { STAGE_A_SLICE(t + 2, 0); STAGE_B_HALF(t + 2, 0); }
    __builtin_amdgcn_sched_barrier(0);
    __builtin_amdgcn_s_setprio(1);
    asm volatile("s_waitcnt lgkmcnt(4)" ::: "memory");   // af set1 done
    __builtin_amdgcn_sched_barrier(0);
    MFMA_HALF(2, 1, 0);
    MFMA_HALF(2, 1, 1);
    __builtin_amdgcn_s_setprio(0);
    __builtin_amdgcn_s_barrier();

    // ---------------- phase 2 (acc rows 4,5; af set 0) ----------------
    af[1][0][0] = LDA_(curo, 6, 0); af[1][0][1] = LDA_(curo, 6, 1);
    af[1][1][0] = LDA_(curo, 7, 0); af[1][1][1] = LDA_(curo, 7, 1);
    __builtin_amdgcn_sched_barrier(0);
    if (t + 2 < NT) { STAGE_A_SLICE(t + 2, 1); STAGE_B_HALF(t + 2, 1); }
    __builtin_amdgcn_sched_barrier(0);
    __builtin_amdgcn_s_setprio(1);
    asm volatile("s_waitcnt lgkmcnt(4)" ::: "memory");   // af set0 done
    __builtin_amdgcn_sched_barrier(0);
    MFMA_HALF(4, 0, 0);
    MFMA_HALF(4, 0, 1);
    __builtin_amdgcn_s_setprio(0);
    __builtin_amdgcn_s_barrier();

    // ---------------- phase 3 (acc rows 6,7; af set 1) ----------------
    // boundary: retire ALL of tile t+1 before staging; publish via end barrier
    if (t < NT - 2) {
      asm volatile("s_waitcnt vmcnt(6)" ::: "memory");
    } else if (t == NT - 2) {
      asm volatile("s_waitcnt vmcnt(0)" ::: "memory");
    }
    __builtin_amdgcn_sched_barrier(0);
    if (t + 2 < NT) STAGE_A_SLICE(t + 2, 2);
    __builtin_amdgcn_sched_barrier(0);
    __builtin_amdgcn_s_setprio(1);
    asm volatile("s_waitcnt lgkmcnt(0)" ::: "memory");   // af set1 done
    __builtin_amdgcn_sched_barrier(0);
    MFMA_HALF(6, 1, 0);
    MFMA_HALF(6, 1, 1);
    __builtin_amdgcn_s_setprio(0);
    __builtin_amdgcn_s_barrier();
  }

  // ---------------- epilogue: in-lane gate fusion ----------------
  const int n_out = (bx * 4 + wc) * 16 + lr;   // hidden index 0..1023
  const float bfv = biasc[n_out];
  const float biv = biasc[1024 + n_out];
  const float bov = biasc[2048 + n_out];
  const float bcv = biasc[3072 + n_out];
  const int q0 = (lane >> 4) * 4;

#pragma unroll
  for (int m = 0; m < 8; ++m) {
    int row0 = by * 256 + wr * 128 + m * 16 + q0;
#pragma unroll
    for (int q = 0; q < 4; ++q) {
      int row = row0 + q;
      float pf = acc[m][0][q] + bfv;
      float pi = acc[m][1][q] + biv;
      float po = acc[m][2][q] + bov;
      float pc = acc[m][3][q] + bcv;
      float fg = sigmoid_f(pf);
      float ig = sigmoid_f(pi);
      float og = sigmoid_f(po);
      float cg = tanh_f(pc);
      float cold = cell[(size_t)row * NH + n_out];
      float cn = fg * cold + ig * cg;
      float hn = og * tanh_f(cn);
      outH[(size_t)row * NH + n_out] = hn;
      outC[(size_t)row * NH + n_out] = cn;
    }
  }
}

extern "C" void kernel_launch(void* const* d_in, const int* in_sizes, int n_in,
                              void* d_out, int out_size, void* d_ws, size_t ws_size,
                              hipStream_t stream) {
  const float* x    = (const float*)d_in[0];
  const float* h    = (const float*)d_in[1];
  const float* cell = (const float*)d_in[2];
  WPtrs wp; BPtrs bp;
  for (int g = 0; g < 4; ++g) {
    wp.wx[g] = (const float*)d_in[3 + 2 * g];
    bp.bx[g] = (const float*)d_in[4 + 2 * g];
    wp.wh[g] = (const float*)d_in[11 + 2 * g];
    bp.bh[g] = (const float*)d_in[12 + 2 * g];
  }

  char* ws = (char*)d_ws;
  __hip_bfloat16* Acat = (__hip_bfloat16*)ws;
  __hip_bfloat16* Bcat = (__hip_bfloat16*)(ws + (size_t)BATCH * KCAT * 2);
  float* biasc = (float*)(ws + (size_t)BATCH * KCAT * 2 + (size_t)NJ * KCAT * 2);

  float* outH = (float*)d_out;
  float* outC = outH + (size_t)BATCH * NH;

  pack_all<<<8208, 256, 0, stream>>>(x, h, wp, bp, Acat, Bcat, biasc);

  lstm_gemm8<<<256, 512, 0, stream>>>((const unsigned short*)Acat,
                                      (const unsigned short*)Bcat,
                                      biasc, cell, outH, outC);
}

// Round 6
// 85.688 us; speedup vs baseline: 1.5012x; 1.0028x over previous
//
#include <hip/hip_runtime.h>
#include <hip/hip_bf16.h>

#define BATCH 4096
#define NH    1024
#define KCAT  2048   // x(1024) | h(1024)
#define NJ    4096   // 4 gates * 1024
#define NT    (KCAT / 64)   // 32 K-tiles
#define NIT   (NT / 2)      // 16 iterations (2 K-tiles each)

typedef __bf16 bf16x8 __attribute__((ext_vector_type(8)));
typedef float  f32x4  __attribute__((ext_vector_type(4)));
typedef unsigned short u16x8 __attribute__((ext_vector_type(8)));

struct WPtrs { const float* wx[4]; const float* wh[4]; };
struct BPtrs { const float* bx[4]; const float* bh[4]; };

__device__ __forceinline__ unsigned short f2b(float f) {
  union { float f; unsigned u; } v; v.f = f;
  return (unsigned short)((v.u + 0x7fffu + ((v.u >> 16) & 1u)) >> 16);  // RNE
}

__device__ __forceinline__ void gload_lds16(const void* g, void* l) {
  __builtin_amdgcn_global_load_lds(
      (const __attribute__((address_space(1))) unsigned int*)g,
      (__attribute__((address_space(3))) unsigned int*)l, 16, 0, 0);
}

__device__ __forceinline__ float sigmoid_f(float x) {
  x = fminf(fmaxf(x, -30.f), 30.f);
  return 1.f / (1.f + __expf(-x));
}
__device__ __forceinline__ float tanh_f(float x) {
  x = fminf(fmaxf(x, -15.f), 15.f);
  float e = __expf(2.f * x);
  return (e - 1.f) / (e + 1.f);
}

// ---------------- fused pack kernel (A-cat, B-cat, bias in one launch) -----
__global__ __launch_bounds__(256) void pack_all(
    const float* __restrict__ x, const float* __restrict__ h,
    WPtrs W, BPtrs B,
    __hip_bfloat16* __restrict__ Acat, __hip_bfloat16* __restrict__ Bcat,
    float* __restrict__ biasc) {
  int bid = blockIdx.x;
  if (bid < 4096) {            // A_cat: [row][k], k<1024 -> x, else h
    int t = bid * 256 + threadIdx.x;
    int base = t * 8;
    int row = base >> 11;
    int k   = base & 2047;
    const float* src = (k < 1024) ? (x + (size_t)row * 1024 + k)
                                  : (h + (size_t)row * 1024 + (k - 1024));
    float4 v0 = ((const float4*)src)[0];
    float4 v1 = ((const float4*)src)[1];
    u16x8 o;
    o[0]=f2b(v0.x); o[1]=f2b(v0.y); o[2]=f2b(v0.z); o[3]=f2b(v0.w);
    o[4]=f2b(v1.x); o[5]=f2b(v1.y); o[6]=f2b(v1.z); o[7]=f2b(v1.w);
    *(u16x8*)((unsigned short*)Acat + base) = o;
  } else if (bid < 8192) {     // B_cat: j = (n>>4)*64 + g*16 + (n&15)
    int t = (bid - 4096) * 256 + threadIdx.x;
    int base = t * 8;
    int j = base >> 11;
    int k = base & 2047;
    int n = ((j >> 6) << 4) + (j & 15);
    int g = (j >> 4) & 3;
    const float* src = (k < 1024) ? (W.wx[g] + (size_t)n * 1024 + k)
                                  : (W.wh[g] + (size_t)n * 1024 + (k - 1024));
    float4 v0 = ((const float4*)src)[0];
    float4 v1 = ((const float4*)src)[1];
    u16x8 o;
    o[0]=f2b(v0.x); o[1]=f2b(v0.y); o[2]=f2b(v0.z); o[3]=f2b(v0.w);
    o[4]=f2b(v1.x); o[5]=f2b(v1.y); o[6]=f2b(v1.z); o[7]=f2b(v1.w);
    *(u16x8*)((unsigned short*)Bcat + base) = o;
  } else {                     // bias: biasc[g*1024+n] = bx[g][n]+bh[g][n]
    int i = (bid - 8192) * 256 + threadIdx.x;   // 0..4095
    int g = i >> 10, n = i & 1023;
    biasc[i] = B.bx[g][n] + B.bh[g][n];
  }
}

// ------------- 256x256 faithful-m201 8-phase GEMM + LSTM epilogue ----------
// 2 K-tiles per iteration (p1-4: buf0/tile t0; p5-8: buf1/tile t0+1).
// Each phase = quadrant (mq,nq) of the wave's 128x64 tile over full K=64:
// 16 MFMA; ds-reads [12,4,8,0] per tile; 1 half-tile staged per phase;
// barrier -> lgkmcnt(0) -> setprio(1) -> MFMA -> setprio(0) -> barrier.
// Stagger: p1,2: A(t0+1); p3,4: B(t0+2); p5,6: A(t0+2); p7,8: B(t0+3).
// Safety: each stage targets a region whose readers are lgkm-certified by an
// earlier end-of-phase barrier. vmcnt(4) at p4 (tile t0+1 ready for p5) and
// p8 (tile t0+2 ready for next p1); tail (it=15): p4 vmcnt(0), p8 no wait.

#define STAGE_A_HALF(T, H)                                                      \
  {                                                                             \
    _Pragma("unroll")                                                           \
    for (int i_ = 0; i_ < 2; ++i_) {                                            \
      gload_lds16(Ag + (size_t)((H)*128 + i_*64 + strow) * KCAT + (T)*64 +      \
                      stchnk * 8,                                               \
                  &smem[((T)&1)*32768 + (H)*8192 + i_*4096 + w*512]);           \
    }                                                                           \
  }
#define STAGE_B_HALF(T, H)                                                      \
  {                                                                             \
    _Pragma("unroll")                                                           \
    for (int i_ = 0; i_ < 2; ++i_) {                                            \
      gload_lds16(Bg + (size_t)((H)*128 + i_*64 + strow) * KCAT + (T)*64 +      \
                      stchnk * 8,                                               \
                  &smem[((T)&1)*32768 + 16384 + (H)*8192 + i_*4096 + w*512]);   \
    }                                                                           \
  }

#define READ_A(BUFO, MQ)                                                        \
  {                                                                             \
    _Pragma("unroll")                                                           \
    for (int mf_ = 0; mf_ < 4; ++mf_) {                                         \
      af[mf_][0] = *(const bf16x8*)(smc + (BUFO) + arow0 +                      \
                                    ((MQ)*4 + mf_)*2048 + colb0);               \
      af[mf_][1] = *(const bf16x8*)(smc + (BUFO) + arow0 +                      \
                                    ((MQ)*4 + mf_)*2048 + colb1);               \
    }                                                                           \
  }
#define READ_B(BUFO, NQ)                                                        \
  {                                                                             \
    _Pragma("unroll")                                                           \
    for (int nf_ = 0; nf_ < 2; ++nf_) {                                         \
      bfr[NQ][nf_][0] = *(const bf16x8*)(smc + (BUFO) + brow0 +                 \
                                         ((NQ)*2 + nf_)*2048 + colb0);          \
      bfr[NQ][nf_][1] = *(const bf16x8*)(smc + (BUFO) + brow0 +                 \
                                         ((NQ)*2 + nf_)*2048 + colb1);          \
    }                                                                           \
  }
#define MFMA_Q(MQ, NQ)                                                          \
  {                                                                             \
    _Pragma("unroll")                                                           \
    for (int ks_ = 0; ks_ < 2; ++ks_)                                           \
      _Pragma("unroll")                                                         \
      for (int mf_ = 0; mf_ < 4; ++mf_)                                         \
        _Pragma("unroll")                                                       \
        for (int nf_ = 0; nf_ < 2; ++nf_)                                       \
          acc[(MQ)*4 + mf_][(NQ)*2 + nf_] =                                     \
              __builtin_amdgcn_mfma_f32_16x16x32_bf16(                          \
                  af[mf_][ks_], bfr[NQ][nf_][ks_],                              \
                  acc[(MQ)*4 + mf_][(NQ)*2 + nf_], 0, 0, 0);                    \
  }

#define BAR    __builtin_amdgcn_s_barrier()
#define LGKM0  { asm volatile("s_waitcnt lgkmcnt(0)" ::: "memory");             \
                 __builtin_amdgcn_sched_barrier(0); }
#define LGKM8  asm volatile("s_waitcnt lgkmcnt(8)" ::: "memory")
#define PRIO1  __builtin_amdgcn_s_setprio(1)
#define PRIO0  __builtin_amdgcn_s_setprio(0)

__global__ __launch_bounds__(512, 2) void lstm_gemm8(
    const unsigned short* __restrict__ Acat,
    const unsigned short* __restrict__ Bcat,
    const float* __restrict__ biasc,
    const float* __restrict__ cell,
    float* __restrict__ outH, float* __restrict__ outC) {
  __shared__ unsigned short smem[65536];  // 128 KiB

  const int tid  = threadIdx.x;
  const int w    = tid >> 6;    // 0..7
  const int lane = tid & 63;
  const int wr   = w >> 2;      // 0..1 (M)
  const int wc   = w & 3;       // 0..3 (N)
  const int lr   = lane & 15;
  const int cb0  = ((lane >> 4) & 3) * 16;   // 16B chunk within row
  const int sx   = (lr & 7) << 4;            // read-side swizzle XOR

  // XCD-aware bijective swizzle (256 blocks, 8 XCDs)
  const int bid = blockIdx.x;
  const int s   = (bid & 7) * 32 + (bid >> 3);
  const int bx  = s & 15;
  const int by  = s >> 4;

  const unsigned short* Ag = Acat + (size_t)(by * 256) * KCAT;
  const unsigned short* Bg = Bcat + (size_t)(bx * 256) * KCAT;

  // staging source mapping (pre-swizzled global chunk)
  const int strow  = w * 8 + (lane >> 3);              // row within 128-row half
  const int stchnk = (lane & 7) ^ ((lane >> 3) & 7);   // swizzled src chunk

  // per-thread read base byte offsets into smem
  const int arow0 = (wr * 128 + lr) * 128;          // + mp*2048 + colb
  const int brow0 = 32768 + (wc * 64 + lr) * 128;   // + n*2048 + colb
  const int colb0 = cb0 ^ sx;
  const int colb1 = (64 + cb0) ^ sx;
  const char* smc = (const char*)smem;

  f32x4 acc[8][4] = {};
  bf16x8 af[4][2];       // current A-subtile (one mq quadrant, full K=64)
  bf16x8 bfr[2][2][2];   // [nq][nf][ks] — both B-subtiles of current tile

  // prologue: tile0 A+B, tile1 B; retire tile0 (leave B(1) 4 loads in flight)
  STAGE_A_HALF(0, 0);
  STAGE_A_HALF(0, 1);
  STAGE_B_HALF(0, 0);
  STAGE_B_HALF(0, 1);
  STAGE_B_HALF(1, 0);
  STAGE_B_HALF(1, 1);
  asm volatile("s_waitcnt vmcnt(4)" ::: "memory");
  __builtin_amdgcn_sched_barrier(0);
  BAR;

  for (int it = 0; it < NIT; ++it) {
    const int t0 = 2 * it;
    const bool full = (t0 + 2 < NT);

    // ---------------- K-tile t0 (buf0) ----------------
    // p1: quadrant (0,0)
    READ_A(0, 0);
    READ_B(0, 0);
    STAGE_A_HALF(t0 + 1, 0);
    LGKM8;
    BAR; LGKM0;
    PRIO1; MFMA_Q(0, 0); PRIO0;
    BAR;
    // p2: quadrant (0,1)
    READ_B(0, 1);
    STAGE_A_HALF(t0 + 1, 1);
    BAR; LGKM0;
    PRIO1; MFMA_Q(0, 1); PRIO0;
    BAR;
    // p3: quadrant (1,0)
    READ_A(0, 1);
    if (full) STAGE_B_HALF(t0 + 2, 0);
    BAR; LGKM0;
    PRIO1; MFMA_Q(1, 0); PRIO0;
    BAR;
    // p4: quadrant (1,1) + boundary vmcnt (tile t0+1 ready for p5)
    if (full) {
      STAGE_B_HALF(t0 + 2, 1);
      asm volatile("s_waitcnt vmcnt(4)" ::: "memory");
    } else {
      asm volatile("s_waitcnt vmcnt(0)" ::: "memory");
    }
    __builtin_amdgcn_sched_barrier(0);
    BAR; LGKM0;
    PRIO1; MFMA_Q(1, 1); PRIO0;
    BAR;

    // ---------------- K-tile t0+1 (buf1) ----------------
    // p5: quadrant (0,0)
    READ_A(65536, 0);
    READ_B(65536, 0);
    if (full) STAGE_A_HALF(t0 + 2, 0);
    LGKM8;
    BAR; LGKM0;
    PRIO1; MFMA_Q(0, 0); PRIO0;
    BAR;
    // p6: quadrant (0,1)
    READ_B(65536, 1);
    if (full) STAGE_A_HALF(t0 + 2, 1);
    BAR; LGKM0;
    PRIO1; MFMA_Q(0, 1); PRIO0;
    BAR;
    // p7: quadrant (1,0)
    READ_A(65536, 1);
    if (full) STAGE_B_HALF(t0 + 3, 0);
    BAR; LGKM0;
    PRIO1; MFMA_Q(1, 0); PRIO0;
    BAR;
    // p8: quadrant (1,1) + boundary vmcnt (tile t0+2 ready for next p1)
    if (full) {
      STAGE_B_HALF(t0 + 3, 1);
      asm volatile("s_waitcnt vmcnt(4)" ::: "memory");
      __builtin_amdgcn_sched_barrier(0);
    }
    BAR; LGKM0;
    PRIO1; MFMA_Q(1, 1); PRIO0;
    BAR;
  }

  // ---------------- epilogue: in-lane gate fusion ----------------
  const int n_out = (bx * 4 + wc) * 16 + lr;   // hidden index 0..1023
  const float bfv = biasc[n_out];
  const float biv = biasc[1024 + n_out];
  const float bov = biasc[2048 + n_out];
  const float bcv = biasc[3072 + n_out];
  const int q0 = (lane >> 4) * 4;

#pragma unroll
  for (int m = 0; m < 8; ++m) {
    int row0 = by * 256 + wr * 128 + m * 16 + q0;
#pragma unroll
    for (int q = 0; q < 4; ++q) {
      int row = row0 + q;
      float pf = acc[m][0][q] + bfv;
      float pi = acc[m][1][q] + biv;
      float po = acc[m][2][q] + bov;
      float pc = acc[m][3][q] + bcv;
      float fg = sigmoid_f(pf);
      float ig = sigmoid_f(pi);
      float og = sigmoid_f(po);
      float cg = tanh_f(pc);
      float cold = cell[(size_t)row * NH + n_out];
      float cn = fg * cold + ig * cg;
      float hn = og * tanh_f(cn);
      outH[(size_t)row * NH + n_out] = hn;
      outC[(size_t)row * NH + n_out] = cn;
    }
  }
}

extern "C" void kernel_launch(void* const* d_in, const int* in_sizes, int n_in,
                              void* d_out, int out_size, void* d_ws, size_t ws_size,
                              hipStream_t stream) {
  const float* x    = (const float*)d_in[0];
  const float* h    = (const float*)d_in[1];
  const float* cell = (const float*)d_in[2];
  WPtrs wp; BPtrs bp;
  for (int g = 0; g < 4; ++g) {
    wp.wx[g] = (const float*)d_in[3 + 2 * g];
    bp.bx[g] = (const float*)d_in[4 + 2 * g];
    wp.wh[g] = (const float*)d_in[11 + 2 * g];
    bp.bh[g] = (const float*)d_in[12 + 2 * g];
  }

  char* ws = (char*)d_ws;
  __hip_bfloat16* Acat = (__hip_bfloat16*)ws;
  __hip_bfloat16* Bcat = (__hip_bfloat16*)(ws + (size_t)BATCH * KCAT * 2);
  float* biasc = (float*)(ws + (size_t)BATCH * KCAT * 2 + (size_t)NJ * KCAT * 2);

  float* outH = (float*)d_out;
  float* outC = outH + (size_t)BATCH * NH;

  pack_all<<<8208, 256, 0, stream>>>(x, h, wp, bp, Acat, Bcat, biasc);

  lstm_gemm8<<<256, 512, 0, stream>>>((const unsigned short*)Acat,
                                      (const unsigned short*)Bcat,
                                      biasc, cell, outH, outC);
}